// Round 11
// baseline (395.345 us; speedup 1.0000x reference)
//
#include <hip/hip_runtime.h>

typedef unsigned short u16;
typedef unsigned int u32;
typedef __attribute__((ext_vector_type(8))) short bf16x8;
typedef __attribute__((ext_vector_type(4))) float f32x4;

__device__ __forceinline__ u16 f2bf(float f) {
  u32 u = __float_as_uint(f);
  u += 0x7fffu + ((u >> 16) & 1u);
  return (u16)(u >> 16);
}
__device__ __forceinline__ float bf2f(short h) {
  return __uint_as_float(((u32)(u16)h) << 16);
}

// ---------------- convert x: f32 -> bf16 (straight) ----------------
__global__ __launch_bounds__(256) void k_cvt(const float* __restrict__ in, u16* __restrict__ out, int n) {
  int idx = (blockIdx.x * 256 + threadIdx.x) * 8;
  if (idx >= n) return;
  float4 a = *(const float4*)&in[idx];
  float4 b = *(const float4*)&in[idx + 4];
  union { u16 h[8]; uint4 v; } t;
  t.h[0] = f2bf(a.x); t.h[1] = f2bf(a.y); t.h[2] = f2bf(a.z); t.h[3] = f2bf(a.w);
  t.h[4] = f2bf(b.x); t.h[5] = f2bf(b.y); t.h[6] = f2bf(b.z); t.h[7] = f2bf(b.w);
  *(uint4*)&out[idx] = t.v;
}

// ---------------- transpose+convert: out[c][r] = bf16(in[r][c]) ----------------
__global__ __launch_bounds__(256) void k_tcvt(const float* __restrict__ in, u16* __restrict__ out, int R, int C) {
  __shared__ u16 T[64 * 72];
  int t = threadIdx.x;
  int r0 = blockIdx.y * 64, c0 = blockIdx.x * 64;
  for (int i = 0; i < 4; i++) {
    int cc = i * 256 + t; int r = cc >> 4; int s = cc & 15;
    float4 v = *(const float4*)&in[(size_t)(r0 + r) * C + c0 + s * 4];
    T[r * 72 + s * 4 + 0] = f2bf(v.x);
    T[r * 72 + s * 4 + 1] = f2bf(v.y);
    T[r * 72 + s * 4 + 2] = f2bf(v.z);
    T[r * 72 + s * 4 + 3] = f2bf(v.w);
  }
  __syncthreads();
  for (int i = 0; i < 2; i++) {
    int cc = i * 256 + t; int c = cc >> 3; int s2 = cc & 7;
    union { u16 h[8]; uint4 v; } tmp;
    for (int e = 0; e < 8; e++) tmp.h[e] = T[(s2 * 8 + e) * 72 + c];
    *(uint4*)&out[(size_t)(c0 + c) * R + r0 + s2 * 8] = tmp.v;
  }
}

// ---------------- transpose v-part of qkv into Vt[512][8192] ----------------
__global__ __launch_bounds__(256) void k_tv(const u16* __restrict__ qkv, u16* __restrict__ vt) {
  __shared__ u16 T[64 * 72];
  int t = threadIdx.x;
  int r0 = blockIdx.y * 64, d0 = blockIdx.x * 64;
  for (int i = 0; i < 2; i++) {
    int cc = i * 256 + t; int r = cc >> 3; int s = cc & 7;
    *(uint4*)&T[r * 72 + s * 8] = *(const uint4*)&qkv[(size_t)(r0 + r) * 1536 + 1024 + d0 + s * 8];
  }
  __syncthreads();
  for (int i = 0; i < 2; i++) {
    int cc = i * 256 + t; int d = cc >> 3; int s2 = cc & 7;
    union { u16 h[8]; uint4 v; } tmp;
    for (int e = 0; e < 8; e++) tmp.h[e] = T[(s2 * 8 + e) * 72 + d];
    *(uint4*)&vt[(size_t)(d0 + d) * 8192 + r0 + s2 * 8] = tmp.v;
  }
}

// ---------------- pack per-tile LDS images: ktile/vtile[jt] = contiguous 32KB each ----------------
__global__ __launch_bounds__(256) void k_pack(const u16* __restrict__ qkv, const u16* __restrict__ vt,
                                              u16* __restrict__ ktile, u16* __restrict__ vtile) {
  const int jt = blockIdx.x;
  const int t = threadIdx.x;
  const int tok0 = jt * 32;
  uint4* kd = (uint4*)(ktile + (size_t)jt * 16384);
  uint4* vd = (uint4*)(vtile + (size_t)jt * 16384);
#pragma unroll
  for (int i = 0; i < 8; i++) {
    int cc = i * 256 + t;
    int r = cc >> 6, u = cc & 63;
    int su = (u & 56) | ((u & 7) ^ (r & 7));
    kd[cc] = *(const uint4*)&qkv[(size_t)(tok0 + r) * 1536 + 512 + su * 8];
  }
#pragma unroll
  for (int i = 0; i < 8; i++) {
    int cc = i * 256 + t;
    int tile = cc >> 6, u = (cc >> 4) & 3, dl = cc & 15;
    int d = tile * 16 + dl;
    vd[cc] = *(const uint4*)&vt[(size_t)d * 8192 + tok0 + u * 8];
  }
}

// ---------------- GEMM (m97 structure) ----------------
__global__ __launch_bounds__(256) void k_gemm(const u16* __restrict__ A, const u16* __restrict__ Bt,
                                              const float* __restrict__ bias,
                                              u16* __restrict__ Cb, float* __restrict__ Cf,
                                              int M, int N, int K) {
  __shared__ u16 As[128 * 64];
  __shared__ u16 Bs[128 * 64];
  const int t = threadIdx.x;
  const int l = t & 63, w = t >> 6;
  const int l16 = l & 15, g = l >> 4;
  const int m0 = blockIdx.y * 128, n0 = blockIdx.x * 128;
  const int wr = (w >> 1) * 64, wc = (w & 1) * 64;
  f32x4 acc[4][4] = {};
  for (int kk = 0; kk < K; kk += 64) {
    __syncthreads();
#pragma unroll
    for (int i = 0; i < 4; i++) {
      int c = i * 256 + t;
      int r = c >> 3, g2 = c & 7;
      int sg = g2 ^ (r & 7);
      __builtin_amdgcn_global_load_lds(
          (const __attribute__((address_space(1))) u32*)(A + (size_t)(m0 + r) * K + kk + sg * 8),
          (__attribute__((address_space(3))) u32*)&As[c * 8], 16, 0, 0);
      __builtin_amdgcn_global_load_lds(
          (const __attribute__((address_space(1))) u32*)(Bt + (size_t)(n0 + r) * K + kk + sg * 8),
          (__attribute__((address_space(3))) u32*)&Bs[c * 8], 16, 0, 0);
    }
    __syncthreads();
#pragma unroll
    for (int kh = 0; kh < 2; kh++) {
      bf16x8 a[4];
#pragma unroll
      for (int mi = 0; mi < 4; mi++) {
        int row = wr + 16 * mi + l16;
        int s = (kh * 4 + g) ^ (row & 7);
        a[mi] = *(const bf16x8*)&As[row * 64 + s * 8];
      }
#pragma unroll
      for (int ni = 0; ni < 4; ni++) {
        int row = wc + 16 * ni + l16;
        int s = (kh * 4 + g) ^ (row & 7);
        bf16x8 b = *(const bf16x8*)&Bs[row * 64 + s * 8];
#pragma unroll
        for (int mi = 0; mi < 4; mi++)
          acc[mi][ni] = __builtin_amdgcn_mfma_f32_16x16x32_bf16(a[mi], b, acc[mi][ni], 0, 0, 0);
      }
    }
  }
#pragma unroll
  for (int ni = 0; ni < 4; ni++) {
    int col = n0 + wc + 16 * ni + l16;
    float bv = bias[col];
#pragma unroll
    for (int mi = 0; mi < 4; mi++) {
      int row0 = m0 + wr + 16 * mi + 4 * g;
#pragma unroll
      for (int r = 0; r < 4; r++) {
        float v = acc[mi][ni][r] + bv;
        if (Cf) Cf[(size_t)(row0 + r) * N + col] = v;
        else    Cb[(size_t)(row0 + r) * N + col] = f2bf(v);
      }
    }
  }
}

// ---------------- flash v11: v10 compute + phase-offset counted-vmcnt pipeline ----------------
// Per step (steady state), per wave (4 K-loads then 4 V-loads issued per tile):
//   vmcnt(4) [K(j) done] ; barrier ; QK ; barrier ; issue K(j+1) ;
//   vmcnt(4) [V(j) done] ; barrier ; softmax+PV ; barrier ; issue V(j+1)
// No vmcnt(0) drain in the loop: each tile's loads land under a compute phase.
__global__ __launch_bounds__(512, 2) void k_flash11(const u16* __restrict__ qkv,
                                                    const u16* __restrict__ ktile, const u16* __restrict__ vtile,
                                                    u16* __restrict__ opA, u16* __restrict__ opB,
                                                    u16* __restrict__ opC, float* __restrict__ ml, int lgGq) {
  __shared__ u16 Ks[32 * 512];    // LDS image == ktile[jt] (swizzle baked in)
  __shared__ u16 Vs[32 * 512];    // LDS image == vtile[jt] (subtiling baked in)
  __shared__ u16 Ps[8][16 * 40];  // per-wave P strip [16 q][32 kv], stride 40
  const int cx = blockIdx.x;
  const int c = (lgGq == 2 && cx >= 8) ? 23 - cx : cx;   // XCD-pinning remap (bijective 0..15)
  const int qb = 63 - blockIdx.y;             // long blocks dispatched first
  const int Gq = 1 << lgGq;
  const int a = qb >> lgGq, b = qb & (Gq - 1);
  const int nch = a + 1;
  if (c >= nch) return;
  const int slot = (a + 1) * ((Gq >> 1) * a + b) + c;
  const int CT = Gq << 2;
  const int jlo = c * CT;
  const int jhi = min(jlo + CT, (qb + 1) * 4);
  const int t = threadIdx.x;
  const int l = t & 63, w = t >> 6;
  const int l16 = l & 15, g = l >> 4;
  const int q0 = qb * 128;
  const int wq = q0 + 16 * w;                 // wave's first q row
  const float scale = 0.044194173824159216f;  // 1/sqrt(512)

  auto stageK = [&](int jt) {
    const u16* src = ktile + (size_t)jt * 16384;
#pragma unroll
    for (int i = 0; i < 4; i++) {
      int cc = i * 512 + t;
      __builtin_amdgcn_global_load_lds(
          (const __attribute__((address_space(1))) u32*)(src + cc * 8),
          (__attribute__((address_space(3))) u32*)&Ks[cc * 8], 16, 0, 0);
    }
  };
  auto stageV = [&](int jt) {
    const u16* src = vtile + (size_t)jt * 16384;
#pragma unroll
    for (int i = 0; i < 4; i++) {
      int cc = i * 512 + t;
      __builtin_amdgcn_global_load_lds(
          (const __attribute__((address_space(1))) u32*)(src + cc * 8),
          (__attribute__((address_space(3))) u32*)&Vs[cc * 8], 16, 0, 0);
    }
  };

  // hoist Q A-fragments (64 VGPR)
  bf16x8 qa[16];
#pragma unroll
  for (int ks = 0; ks < 16; ks++)
    qa[ks] = *(const bf16x8*)&qkv[(size_t)(wq + l16) * 1536 + ks * 32 + g * 8];

  f32x4 acc[32] = {};                          // O: col = 16db+l16, row = wq+4g+r
  float m_st[4], l_st[4];
#pragma unroll
  for (int r = 0; r < 4; r++) { m_st[r] = -1.0e30f; l_st[r] = 0.f; }

  stageK(jlo);                                 // outstanding/wave: K:4
  stageV(jlo);                                 // outstanding/wave: K:4 + V:4

  for (int jt = jlo; jt < jhi; ++jt) {
    const int tok0 = jt * 32;
    const int jn = (jt + 1 < jhi) ? jt + 1 : jlo;   // dead prefetch on last iter keeps counts uniform

    // ---- K(jt) ready: wait 4 oldest (K) retired, V(jt) still in flight ----
    asm volatile("s_waitcnt vmcnt(4)" ::: "memory");
    __builtin_amdgcn_s_barrier();
    __builtin_amdgcn_sched_barrier(0);

    // ---- QK^T: 16 rows x 32 cols, K=512, 4 independent chains (ks parity) ----
    f32x4 S0a = {0.f,0.f,0.f,0.f}, S0b = {0.f,0.f,0.f,0.f};
    f32x4 S1a = {0.f,0.f,0.f,0.f}, S1b = {0.f,0.f,0.f,0.f};
    __builtin_amdgcn_s_setprio(1);
#pragma unroll
    for (int ks = 0; ks < 16; ks++) {
      int u = 4 * ks + g;
      int su = (u & 56) | ((u & 7) ^ (l16 & 7));
      bf16x8 k0 = *(const bf16x8*)&Ks[l16 * 512 + su * 8];
      bf16x8 k1 = *(const bf16x8*)&Ks[(16 + l16) * 512 + su * 8];
      if (ks & 1) {
        S0b = __builtin_amdgcn_mfma_f32_16x16x32_bf16(qa[ks], k0, S0b, 0, 0, 0);
        S1b = __builtin_amdgcn_mfma_f32_16x16x32_bf16(qa[ks], k1, S1b, 0, 0, 0);
      } else {
        S0a = __builtin_amdgcn_mfma_f32_16x16x32_bf16(qa[ks], k0, S0a, 0, 0, 0);
        S1a = __builtin_amdgcn_mfma_f32_16x16x32_bf16(qa[ks], k1, S1a, 0, 0, 0);
      }
    }
    __builtin_amdgcn_s_setprio(0);
    __builtin_amdgcn_s_barrier();              // all waves done reading Ks
    stageK(jn);                                // issue next K into Ks; lands under softmax+PV

    f32x4 S0, S1;
#pragma unroll
    for (int r = 0; r < 4; r++) { S0[r] = (S0a[r] + S0b[r]) * scale; S1[r] = (S1a[r] + S1b[r]) * scale; }
    // ---- causal mask (wave-uniform skip when tile fully visible) ----
    if (tok0 + 31 > wq) {
      const int kv0 = tok0 + l16, kv1 = tok0 + 16 + l16;
      const int qp = wq + 4 * g;
#pragma unroll
      for (int r = 0; r < 4; r++) {
        if (kv0 > qp + r) S0[r] = -1e10f;
        if (kv1 > qp + r) S1[r] = -1e10f;
      }
    }
    // ---- V(jt) ready: wait until only K(jn):4 outstanding ----
    asm volatile("s_waitcnt vmcnt(4)" ::: "memory");
    __builtin_amdgcn_s_barrier();
    __builtin_amdgcn_sched_barrier(0);

    // ---- wave-local online softmax with defer-max (THR=6) ----
    float pm[4];
#pragma unroll
    for (int r = 0; r < 4; r++) {
      float v = fmaxf(S0[r], S1[r]);
#pragma unroll
      for (int off = 1; off < 16; off <<= 1) v = fmaxf(v, __shfl_xor(v, off));
      pm[r] = v;
    }
    float sc[4] = {1.f, 1.f, 1.f, 1.f};
    int need = (pm[0] > m_st[0] + 6.f) | (pm[1] > m_st[1] + 6.f) |
               (pm[2] > m_st[2] + 6.f) | (pm[3] > m_st[3] + 6.f);
    if (__any(need)) {
#pragma unroll
      for (int r = 0; r < 4; r++) {
        float mn = fmaxf(m_st[r], pm[r]);
        sc[r] = __expf(m_st[r] - mn);
        m_st[r] = mn;
      }
#pragma unroll
      for (int db = 0; db < 32; db++)
#pragma unroll
        for (int r = 0; r < 4; r++) acc[db][r] *= sc[r];
    }
#pragma unroll
    for (int r = 0; r < 4; r++) {
      float p0 = __expf(S0[r] - m_st[r]);
      float p1 = __expf(S1[r] - m_st[r]);
      Ps[w][(4 * g + r) * 40 + l16] = f2bf(p0);
      Ps[w][(4 * g + r) * 40 + 16 + l16] = f2bf(p1);
      float ps = p0 + p1;
#pragma unroll
      for (int off = 1; off < 16; off <<= 1) ps += __shfl_xor(ps, off);
      l_st[r] = l_st[r] * sc[r] + ps;
    }
    // ---- PV: O[16x512] += P[16x32] @ V[32x512]; V reads conflict-free ----
    bf16x8 pa = *(const bf16x8*)&Ps[w][l16 * 40 + g * 8];
    __builtin_amdgcn_s_setprio(1);
#pragma unroll
    for (int db = 0; db < 32; db++) {
      bf16x8 vb = *(const bf16x8*)&Vs[db * 512 + g * 128 + l16 * 8];
      acc[db] = __builtin_amdgcn_mfma_f32_16x16x32_bf16(pa, vb, acc[db], 0, 0, 0);
    }
    __builtin_amdgcn_s_setprio(0);
    __builtin_amdgcn_s_barrier();              // all waves done reading Vs
    stageV(jn);                                // issue next V into Vs; lands under next QK
  }

  // ---- epilogue: vectorized unnormalized partials + (m,l) ----
  u16* op = slot < 152 ? opA + (size_t)slot * 65536
          : slot < 288 ? opB + (size_t)(slot - 152) * 65536
                       : opC + (size_t)(slot - 288) * 65536;
  uint4* opw = (uint4*)op;
#pragma unroll
  for (int db2 = 0; db2 < 16; db2++) {
    union { u16 h[8]; uint4 v; } pk;
#pragma unroll
    for (int j = 0; j < 8; j++) pk.h[j] = f2bf(acc[2 * db2 + (j >> 2)][j & 3]);
    opw[w * 1024 + db2 * 64 + l] = pk.v;
  }
  if (l16 == 0) {
#pragma unroll
    for (int r = 0; r < 4; r++) {
      int rowl = 16 * w + 4 * g + r;
      ml[slot * 256 + rowl * 2 + 0] = m_st[r];
      ml[slot * 256 + rowl * 2 + 1] = l_st[r];
    }
  }
}

// ---------------- combine partials -> normalized O (bf16); nch <= 16 ----------------
__global__ __launch_bounds__(512) void k_comb5(const u16* __restrict__ opA, const u16* __restrict__ opB,
                                               const u16* __restrict__ opC, const float* __restrict__ ml,
                                               u16* __restrict__ Ob, int lgGq) {
  __shared__ float wgtS[16][128];
  const int qb = blockIdx.x;
  const int Gq = 1 << lgGq;
  const int a = qb >> lgGq, b = qb & (Gq - 1);
  const int nch = a + 1;
  const int base = (a + 1) * ((Gq >> 1) * a + b);
  const int t = threadIdx.x;
  if (t < 128) {
    float M = -3.0e38f;
    for (int c2 = 0; c2 < nch; c2++) M = fmaxf(M, ml[(base + c2) * 256 + t * 2]);
    float L = 0.f;
    for (int c2 = 0; c2 < nch; c2++) {
      float e = __expf(ml[(base + c2) * 256 + t * 2] - M);
      L += e * ml[(base + c2) * 256 + t * 2 + 1];
      wgtS[c2][t] = e;
    }
    float inv = 1.0f / L;
    for (int c2 = 0; c2 < nch; c2++) wgtS[c2][t] *= inv;
  }
  __syncthreads();
  const int l = t & 63, w = t >> 6;
  const int l16 = l & 15, g = l >> 4;
#pragma unroll 4
  for (int db2 = 0; db2 < 16; db2++) {
    float o[8] = {};
    for (int c2 = 0; c2 < nch; c2++) {
      int slot = base + c2;
      const uint4* src = slot < 152 ? (const uint4*)(opA + (size_t)slot * 65536)
                       : slot < 288 ? (const uint4*)(opB + (size_t)(slot - 152) * 65536)
                                    : (const uint4*)(opC + (size_t)(slot - 288) * 65536);
      uint4 v = src[w * 1024 + db2 * 64 + l];
      union { uint4 u; u16 h[8]; } un; un.u = v;
#pragma unroll
      for (int j = 0; j < 8; j++) o[j] += wgtS[c2][16 * w + 4 * g + (j & 3)] * bf2f(un.h[j]);
    }
#pragma unroll
    for (int j = 0; j < 8; j++) {
      int row = qb * 128 + 16 * w + 4 * g + (j & 3);
      int col = 32 * db2 + 16 * (j >> 2) + l16;
      Ob[(size_t)row * 512 + col] = f2bf(o[j]);
    }
  }
}

extern "C" void kernel_launch(void* const* d_in, const int* in_sizes, int n_in,
                              void* d_out, int out_size, void* d_ws, size_t ws_size,
                              hipStream_t stream) {
  const float* x     = (const float*)d_in[0];
  const float* w_qkv = (const float*)d_in[1];
  const float* b_qkv = (const float*)d_in[2];
  const float* w_out = (const float*)d_in[3];
  const float* b_out = (const float*)d_in[4];
  float* out = (float*)d_out;
  char* ws = (char*)d_ws;
  // base layout
  u16* xb    = (u16*)(ws);               // [8192][1024] bf16 (dead after gemm1 -> opA)
  u16* wqkvT = (u16*)(ws + 16777216);    // [1536][1024] bf16 (dead after gemm1 -> opA)
  u16* woutT = (u16*)(ws + 19922944);    // [1024][512]  bf16
  u16* qkv   = (u16*)(ws + 20971520);    // [8192][1536] bf16 (ends 46137344)
  u16* ktile = (u16*)(ws + 46137344);    // 256 x 32KB packed K tiles (ends 54525952)
  u16* vtile = (u16*)(ws + 54525952);    // 256 x 32KB packed V tiles (ends 62914560)
  u16* vt    = (u16*)(ws + 62914560);    // [512][8192] bf16 TEMP (dead after k_pack -> opB)
  u16* Ob    = (u16*)(ws + 46137344);    // overlays ktile (dead after flash); comb -> gemm2

  // partials: slots x 128 KB. A: [0, 19922944) = 152 slots (xb+wqkvT dead after gemm1);
  // B: [62914560, 80740352) = 136 slots (vt dead after k_pack); C: d_out (256 slots).
  u16* opA = (u16*)ws;
  u16* opB = (u16*)(ws + 62914560);
  u16* opC = (u16*)d_out;
  float* mlp = (float*)(ws + 80740352);
  const int lgGq = (ws_size >= (size_t)81297408) ? 2 : 3;   // 544 slots primary, 288 fallback
  const int maxc = (lgGq == 2) ? 16 : 8;

  k_cvt<<<4096, 256, 0, stream>>>(x, xb, 8192 * 1024);
  k_tcvt<<<dim3(24, 16), 256, 0, stream>>>(w_qkv, wqkvT, 1024, 1536);
  k_tcvt<<<dim3(16, 8), 256, 0, stream>>>(w_out, woutT, 512, 1024);
  k_gemm<<<dim3(12, 64), 256, 0, stream>>>(xb, wqkvT, b_qkv, qkv, nullptr, 8192, 1536, 1024);
  k_tv<<<dim3(8, 128), 256, 0, stream>>>(qkv, vt);
  k_pack<<<256, 256, 0, stream>>>(qkv, vt, ktile, vtile);
  k_flash11<<<dim3(maxc, 64), 512, 0, stream>>>(qkv, ktile, vtile, opA, opB, opC, mlp, lgGq);
  k_comb5<<<64, 512, 0, stream>>>(opA, opB, opC, mlp, Ob, lgGq);
  k_gemm<<<dim3(8, 64), 256, 0, stream>>>(Ob, woutT, b_out, nullptr, out, 8192, 1024, 512);
}